// Round 7
// baseline (286.274 us; speedup 1.0000x reference)
//
#include <hip/hip_runtime.h>
#include <stdint.h>

// ---------------------------------------------------------------------------
// MultiHeadedAttention: B=8, N=1024, E=512, H=8, D_K=64
// bf16 MFMA pipeline. Round 10: qkv_gemm 64x128 -> 128x128 tile (m97-proven
// structure: 4 waves x 64x64 quadrant, acc[4][4], 16 MFMA/K-step/wave) to
// double MFMA amortization of the 2-barrier staging loop. wcast merged into
// codes_kernel (one fewer launch). attn_kernel kept IDENTICAL to round 9
// (measured 76.9 us) as control.
// ---------------------------------------------------------------------------

typedef __attribute__((ext_vector_type(8))) short short8;
typedef __attribute__((ext_vector_type(4))) float floatx4;

#define MFMA16(a, b, c) __builtin_amdgcn_mfma_f32_16x16x32_bf16((a), (b), (c), 0, 0, 0)

static __device__ __forceinline__ unsigned short f2bf(float f) {
  union { float f; unsigned u; } v; v.f = f;
  unsigned r = v.u + 0x7fffu + ((v.u >> 16) & 1u);   // RNE
  return (unsigned short)(r >> 16);
}

// async global->LDS 16B/lane. LDS dest is wave-uniform base + lane*16 (m104).
static __device__ __forceinline__ void gload_lds16(const void* g, void* l) {
  __builtin_amdgcn_global_load_lds((const __attribute__((address_space(1))) unsigned int*)g,
                                   (__attribute__((address_space(3))) unsigned int*)l,
                                   16, 0, 0);
}
// chunk swizzle for unpadded 32-elem-wide bf16 LDS tiles (GEMM staging).
static __device__ __forceinline__ int xsw(int row) { return (row & 3) ^ ((row >> 2) & 3); }

// ---------------- dist+mask -> codes  +  weight cast (merged) ----------------
// Blocks [0,8192): codes. Blocks [8192,9216): fp32->bf16 weight cast.
// codes layout matches the SWAPPED-QK^T attn epilogue: element
//   (q-row = rg*32 + st*16 + c, k-col = kt*128 + ci*16 + hi*4 + r)
// is held by attn lane = hi*16 + c at byte st*32 + ci*4 + r of its 64B block:
//   codesP[ (((b*32+rg)*8 + kt)*64 + lane)*64 + st*32 + ci*4 + r ]
__global__ void codes_kernel(const float* __restrict__ dist, const int* __restrict__ mask,
                             unsigned char* __restrict__ codesP,
                             const float* __restrict__ Wq, const float* __restrict__ Wk,
                             const float* __restrict__ Wv, const float* __restrict__ Wo,
                             unsigned short* __restrict__ o0, unsigned short* __restrict__ o1,
                             unsigned short* __restrict__ o2, unsigned short* __restrict__ o3) {
  if (blockIdx.x >= 8192) {   // ---- weight cast part ----
    int i = (blockIdx.x - 8192) * blockDim.x + threadIdx.x;   // 0..262143
    int w = i >> 16, loc = i & 65535;
    const float* s = (w == 0) ? Wq : (w == 1) ? Wk : (w == 2) ? Wv : Wo;
    unsigned short* d = (w == 0) ? o0 : (w == 1) ? o1 : (w == 2) ? o2 : o3;
    float4 v = ((const float4*)s)[loc];
    ushort4 o;
    o.x = f2bf(v.x); o.y = f2bf(v.y); o.z = f2bf(v.z); o.w = f2bf(v.w);
    ((ushort4*)d)[loc] = o;
    return;
  }
  int t = blockIdx.x * blockDim.x + threadIdx.x;   // over B*N*N/4
  int flat = t << 2;
  int b = flat >> 20;
  int rem = flat & ((1 << 20) - 1);
  int row = rem >> 10;
  int col0 = rem & 1023;                            // multiple of 4
  float4 d4 = ((const float4*)dist)[t];
  int4 m4 = ((const int4*)mask)[t];
  float dv[4] = {d4.x, d4.y, d4.z, d4.w};
  int mv[4] = {m4.x, m4.y, m4.z, m4.w};
  int rg = row >> 5;
  int st = (row >> 4) & 1;
  int c = row & 15;
  size_t rowbase = (size_t)(b * 32 + rg) * 32768;   // *8 kt *4096
  int kt = col0 >> 7;
  int colk = col0 & 127;
  int ci = colk >> 4;
  int hi = (colk >> 2) & 3;
  int lane = hi * 16 + c;
  unsigned pack = 0;
#pragma unroll
  for (int u = 0; u < 4; u++) {
    int col = col0 + u;
    float d = dv[u];
    int hmin = (d >= 0.2f) + (d >= 0.3f) + (d >= 0.4f) + (d >= 0.5f) +
               (d >= 0.6f) + (d >= 0.7f) + (d >= 0.8f) + (d >= 0.9f);
    unsigned cc = (unsigned)hmin;
    if (row == 0 || col == 0) cc = 0;
    if (mv[u] == 0) cc = 9;
    pack |= cc << (u * 8);
  }
  *(unsigned*)&codesP[rowbase + (size_t)kt * 4096 + lane * 64 + st * 32 + ci * 4] = pack;
}

// ---------------- fused QKV projection GEMM (128x128 tile) ----------------
// C[m][n] = sum_k A[m][k] * W[n][k] + bias[n];  M=8192, N=512, K=512.
// 4 waves, each owns a 64x64 quadrant: acc[4][4], 16 MFMA per K-step.
// A fp32 (cast fused: 16 fp32/thread/step -> reg-staged, padded LDS);
// B bf16 via gload_lds16 + xsw swizzle. z=0/1: [bh][n][d]; z=2: [bh][d][n].
__global__ __launch_bounds__(256) void qkv_gemm(
    const float* __restrict__ Aq, const float* __restrict__ Ak, const float* __restrict__ Av,
    const unsigned short* __restrict__ Wqp, const unsigned short* __restrict__ Wkp,
    const unsigned short* __restrict__ Wvp,
    const float* __restrict__ bq, const float* __restrict__ bk, const float* __restrict__ bv,
    unsigned short* __restrict__ Qh, unsigned short* __restrict__ Kh,
    unsigned short* __restrict__ Vt) {
  const int z = blockIdx.z;
  const float* A = (z == 0) ? Aq : (z == 1) ? Ak : Av;
  const unsigned short* W = (z == 0) ? Wqp : (z == 1) ? Wkp : Wvp;
  const float* bias = (z == 0) ? bq : (z == 1) ? bk : bv;
  unsigned short* O = (z == 0) ? Qh : (z == 1) ? Kh : Vt;

  __shared__ __align__(16) short As[128 * 40];   // 10.0 KB, padded (reg-staged)
  __shared__ __align__(16) short Bs[128 * 32];   // 8.0 KB, xsw (gload_lds16)
  const int tid = threadIdx.x;
  const int lane = tid & 63;
  const int wave = tid >> 6;
  const int c = lane & 15;
  const int q = lane >> 4;
  const int m0 = blockIdx.x * 128;
  const int n0 = blockIdx.y * 128;
  const int wr = (wave >> 1) * 64;
  const int wc = (wave & 1) * 64;

  floatx4 acc[4][4];
#pragma unroll
  for (int i = 0; i < 4; i++)
#pragma unroll
    for (int j = 0; j < 4; j++) acc[i][j] = (floatx4)(0.0f);

  const int arow = tid >> 1, ach = tid & 1;      // 2 threads/row, 16 fp32 each
  const float* Ab = A + (size_t)(m0 + arow) * 512 + ach * 16;

  for (int k0 = 0; k0 < 512; k0 += 32) {
    __syncthreads();
#pragma unroll
    for (int it = 0; it < 2; it++) {
      int slot = wave * 128 + it * 64 + lane;
      int brow = slot >> 2, bch = slot & 3;
      int g = bch ^ xsw(brow);
      gload_lds16(W + (size_t)(n0 + brow) * 512 + k0 + g * 8,
                  &Bs[(size_t)(wave * 128 + it * 64) * 8]);
    }
    float4 a0 = *(const float4*)(Ab + k0);
    float4 a1 = *(const float4*)(Ab + k0 + 4);
    float4 a2 = *(const float4*)(Ab + k0 + 8);
    float4 a3 = *(const float4*)(Ab + k0 + 12);
    short8 av0, av1;
    av0[0] = (short)f2bf(a0.x); av0[1] = (short)f2bf(a0.y);
    av0[2] = (short)f2bf(a0.z); av0[3] = (short)f2bf(a0.w);
    av0[4] = (short)f2bf(a1.x); av0[5] = (short)f2bf(a1.y);
    av0[6] = (short)f2bf(a1.z); av0[7] = (short)f2bf(a1.w);
    av1[0] = (short)f2bf(a2.x); av1[1] = (short)f2bf(a2.y);
    av1[2] = (short)f2bf(a2.z); av1[3] = (short)f2bf(a2.w);
    av1[4] = (short)f2bf(a3.x); av1[5] = (short)f2bf(a3.y);
    av1[6] = (short)f2bf(a3.z); av1[7] = (short)f2bf(a3.w);
    *(short8*)(&As[arow * 40 + ach * 16]) = av0;
    *(short8*)(&As[arow * 40 + ach * 16 + 8]) = av1;
    __syncthreads();

    short8 af[4], bfv[4];
#pragma unroll
    for (int i = 0; i < 4; i++)
      af[i] = *(const short8*)(&As[(wr + i * 16 + c) * 40 + q * 8]);
#pragma unroll
    for (int j = 0; j < 4; j++) {
      int row = wc + j * 16 + c;
      bfv[j] = *(const short8*)(&Bs[row * 32 + (q ^ xsw(row)) * 8]);
    }
#pragma unroll
    for (int i = 0; i < 4; i++)
#pragma unroll
      for (int j = 0; j < 4; j++)
        acc[i][j] = MFMA16(af[i], bfv[j], acc[i][j]);
  }

#pragma unroll
  for (int i = 0; i < 4; i++) {
    int gm0 = m0 + wr + i * 16 + q * 4;
#pragma unroll
    for (int j = 0; j < 4; j++) {
      int gn = n0 + wc + j * 16 + c;
      float bb = bias[gn];
      int h = gn >> 6, d = gn & 63;
      if (z == 2) {
        int b = gm0 >> 10, n = gm0 & 1023;
        ushort4 pk;
#pragma unroll
        for (int r = 0; r < 4; r++) pk[r] = f2bf(acc[i][j][r] + bb);
        *(ushort4*)(&Vt[(((size_t)(b * 8 + h) * 64 + d) << 10) + n]) = pk;  // [bh][d][n]
      } else {
#pragma unroll
        for (int r = 0; r < 4; r++) {
          int m = gm0 + r;
          int b = m >> 10, n = m & 1023;
          O[((((size_t)(b * 8 + h)) << 10) + n) * 64 + d] = f2bf(acc[i][j][r] + bb);
        }
      }
    }
  }
}

// ---------------- output projection GEMM (bf16 A, fp32 out) ----------------
__global__ __launch_bounds__(256) void out_gemm(const unsigned short* __restrict__ A,
                                                const unsigned short* __restrict__ W,
                                                const float* __restrict__ bias,
                                                float* __restrict__ Out) {
  __shared__ __align__(16) short As[64 * 32];
  __shared__ __align__(16) short Bs[128 * 32];
  const int tid = threadIdx.x;
  const int lane = tid & 63;
  const int wave = tid >> 6;
  const int c = lane & 15;
  const int q = lane >> 4;
  const int m0 = blockIdx.x * 64;
  const int n0 = blockIdx.y * 128;
  const int wr = (wave >> 1) * 32;
  const int wc = (wave & 1) * 64;

  floatx4 acc[2][4];
#pragma unroll
  for (int i = 0; i < 2; i++)
#pragma unroll
    for (int j = 0; j < 4; j++) acc[i][j] = (floatx4)(0.0f);

  for (int k0 = 0; k0 < 512; k0 += 32) {
    __syncthreads();
    {
      int slot = wave * 64 + lane;
      int arow = slot >> 2, ach = slot & 3;
      int g = ach ^ xsw(arow);
      gload_lds16(A + (size_t)(m0 + arow) * 512 + k0 + g * 8, &As[(size_t)(wave * 64) * 8]);
    }
#pragma unroll
    for (int it = 0; it < 2; it++) {
      int slot = wave * 128 + it * 64 + lane;
      int brow = slot >> 2, bch = slot & 3;
      int g = bch ^ xsw(brow);
      gload_lds16(W + (size_t)(n0 + brow) * 512 + k0 + g * 8,
                  &Bs[(size_t)(wave * 128 + it * 64) * 8]);
    }
    __syncthreads();

    short8 af[2], bfv[4];
#pragma unroll
    for (int i = 0; i < 2; i++) {
      int row = wr + i * 16 + c;
      af[i] = *(const short8*)(&As[row * 32 + (q ^ xsw(row)) * 8]);
    }
#pragma unroll
    for (int j = 0; j < 4; j++) {
      int row = wc + j * 16 + c;
      bfv[j] = *(const short8*)(&Bs[row * 32 + (q ^ xsw(row)) * 8]);
    }
#pragma unroll
    for (int i = 0; i < 2; i++)
#pragma unroll
      for (int j = 0; j < 4; j++)
        acc[i][j] = MFMA16(af[i], bfv[j], acc[i][j]);
  }

#pragma unroll
  for (int i = 0; i < 2; i++) {
    int gm0 = m0 + wr + i * 16 + q * 4;
#pragma unroll
    for (int j = 0; j < 4; j++) {
      int gn = n0 + wc + j * 16 + c;
      float bb = bias[gn];
#pragma unroll
      for (int r = 0; r < 4; r++)
        Out[(size_t)(gm0 + r) * 512 + gn] = acc[i][j][r] + bb;
    }
  }
}

// ---------------- software-pipelined flash attention (kt-split) ----------
// IDENTICAL to round 9 (measured 76.9 us) — control while qkv_gemm changes.
__global__ __launch_bounds__(256, 3) void attn_kernel(const unsigned short* __restrict__ Qh,
                                                      const unsigned short* __restrict__ Kh,
                                                      const unsigned short* __restrict__ Vt,
                                                      const unsigned char* __restrict__ codesP,
                                                      unsigned short* __restrict__ AO) {
  __shared__ __align__(16) unsigned short P[4][32 * 132];   // 33 KB, wave-private regions
  const int tid = threadIdx.x;
  const int lane = tid & 63;
  const int wave = tid >> 6;
  const int wsub = wave & 1;     // which 32-row sub-block
  const int whalf = wave >> 1;   // which kt half
  const int c = lane & 15;
  const int q = lane >> 4;
  const int bh = blockIdx.y;
  const int b = bh >> 3;
  const int h = bh & 7;
  const size_t base = (size_t)bh << 16;
  const int rbase = blockIdx.x * 64 + wsub * 32;
  const int rg = rbase >> 5;
  unsigned short* Pw = &P[wave][0];

  // Q A-fragments for both 16-row stripes, held all kernel
  short8 aq[2][2];
#pragma unroll
  for (int st = 0; st < 2; st++)
#pragma unroll
    for (int kk = 0; kk < 2; kk++)
      aq[st][kk] = *(const short8*)(Qh + base + (size_t)(rbase + st * 16 + c) * 64 + kk * 32 + q * 8);

  const unsigned char* cbt = codesP + (size_t)(b * 32 + rg) * 32768 + lane * 64;
  const unsigned short* Kb = Kh + base;
  const unsigned short* Vb = Vt + base;

  float rsum[2] = {0.0f, 0.0f};
  floatx4 o[2][4];
#pragma unroll
  for (int st = 0; st < 2; st++)
#pragma unroll
    for (int ci = 0; ci < 4; ci++) o[st][ci] = (floatx4)(0.0f);

  // ---- prologue: prefetch K fragments for phase 0 (kt=whalf*4, j=0) ----
  short8 bk00, bk01, bk10, bk11;   // [u][kk], u: ci=2j+u
  {
    const unsigned short* Kt0 = Kb + (size_t)(whalf * 4) * 8192;
    bk00 = *(const short8*)(Kt0 + (size_t)(0 * 16 + c) * 64 + 0 * 32 + q * 8);
    bk01 = *(const short8*)(Kt0 + (size_t)(0 * 16 + c) * 64 + 1 * 32 + q * 8);
    bk10 = *(const short8*)(Kt0 + (size_t)(1 * 16 + c) * 64 + 0 * 32 + q * 8);
    bk11 = *(const short8*)(Kt0 + (size_t)(1 * 16 + c) * 64 + 1 * 32 + q * 8);
  }

#pragma unroll
  for (int ph = 0; ph < 16; ph++) {
    const int kt = whalf * 4 + (ph >> 2);
    const int j = ph & 3;
    const unsigned char* cp = cbt + (size_t)kt * 4096;

    // ---- top: V loads for THIS phase (consumed by PV at the bottom) ----
    short8 vv0 = *(const short8*)(Vb + (size_t)(0 * 16 + c) * 1024 + kt * 128 + j * 32 + q * 8);
    short8 vv1 = *(const short8*)(Vb + (size_t)(1 * 16 + c) * 1024 + kt * 128 + j * 32 + q * 8);
    short8 vv2 = *(const short8*)(Vb + (size_t)(2 * 16 + c) * 1024 + kt * 128 + j * 32 + q * 8);
    short8 vv3 = *(const short8*)(Vb + (size_t)(3 * 16 + c) * 1024 + kt * 128 + j * 32 + q * 8);
    uint2 cw0 = *(const uint2*)(cp + j * 8);        // st=0 codes
    uint2 cw1 = *(const uint2*)(cp + 32 + j * 8);   // st=1 codes

    // ---- swapped QK^T on prefetched K: lane holds S[q=c][k] ----
    floatx4 s2[2][2];
    s2[0][0] = (floatx4)(0.0f); s2[0][1] = (floatx4)(0.0f);
    s2[1][0] = (floatx4)(0.0f); s2[1][1] = (floatx4)(0.0f);
    s2[0][0] = MFMA16(bk00, aq[0][0], s2[0][0]);
    s2[1][0] = MFMA16(bk00, aq[1][0], s2[1][0]);
    s2[0][0] = MFMA16(bk01, aq[0][1], s2[0][0]);
    s2[1][0] = MFMA16(bk01, aq[1][1], s2[1][0]);
    s2[0][1] = MFMA16(bk10, aq[0][0], s2[0][1]);
    s2[1][1] = MFMA16(bk10, aq[1][0], s2[1][1]);
    s2[0][1] = MFMA16(bk11, aq[0][1], s2[0][1]);
    s2[1][1] = MFMA16(bk11, aq[1][1], s2[1][1]);

    // ---- prefetch K for the NEXT phase (WAR on bk regs is issue-safe) ----
    if (ph < 15) {
      const int phn = ph + 1;
      const int ktn = whalf * 4 + (phn >> 2);
      const int jn = phn & 3;
      const unsigned short* Ktn = Kb + (size_t)ktn * 8192;
      bk00 = *(const short8*)(Ktn + (size_t)((2 * jn + 0) * 16 + c) * 64 + 0 * 32 + q * 8);
      bk01 = *(const short8*)(Ktn + (size_t)((2 * jn + 0) * 16 + c) * 64 + 1 * 32 + q * 8);
      bk10 = *(const short8*)(Ktn + (size_t)((2 * jn + 1) * 16 + c) * 64 + 0 * 32 + q * 8);
      bk11 = *(const short8*)(Ktn + (size_t)((2 * jn + 1) * 16 + c) * 64 + 1 * 32 + q * 8);
    }

    // ---- exp -> cvt_pk -> b64 P write + scalar row sums ----
#pragma unroll
    for (int st = 0; st < 2; st++) {
#pragma unroll
      for (int u = 0; u < 2; u++) {
        unsigned w = st ? (u ? cw1.y : cw1.x) : (u ? cw0.y : cw0.x);
        float ev[4];
#pragma unroll
        for (int r = 0; r < 4; r++) {
          int code = (w >> (r * 8)) & 0xff;
          float ee = (h >= code) ? exp2f(s2[st][u][r] * 0.1803368801111362f) : 0.0f;
          rsum[st] += ee;
          ev[r] = ee;
        }
        unsigned p0, p1;
        asm("v_cvt_pk_bf16_f32 %0, %1, %2" : "=v"(p0) : "v"(ev[0]), "v"(ev[1]));
        asm("v_cvt_pk_bf16_f32 %0, %1, %2" : "=v"(p1) : "v"(ev[2]), "v"(ev[3]));
        uint2 pk; pk.x = p0; pk.y = p1;
        *(uint2*)(&Pw[(st * 16 + c) * 132 + (2 * j + u) * 16 + q * 4]) = pk;
      }
    }

    __builtin_amdgcn_sched_barrier(0);   // phase waist: write side || read side

    // ---- PV: read back own P (lgkm) x resident V frags ----
    short8 ap0 = *(const short8*)(&Pw[(size_t)c * 132 + j * 32 + q * 8]);
    short8 ap1 = *(const short8*)(&Pw[(size_t)(16 + c) * 132 + j * 32 + q * 8]);
    o[0][0] = MFMA16(ap0, vv0, o[0][0]);
    o[1][0] = MFMA16(ap1, vv0, o[1][0]);
    o[0][1] = MFMA16(ap0, vv1, o[0][1]);
    o[1][1] = MFMA16(ap1, vv1, o[1][1]);
    o[0][2] = MFMA16(ap0, vv2, o[0][2]);
    o[1][2] = MFMA16(ap1, vv2, o[1][2]);
    o[0][3] = MFMA16(ap0, vv3, o[0][3]);
    o[1][3] = MFMA16(ap1, vv3, o[1][3]);
  }

  // ---- merge kt-half partials: waves 2,3 -> LDS, waves 0,1 accumulate ----
  // chunks 0..7 = o[st][ci] (float4), chunk 8 = rsum[0..1] (float2). 18 KB.
  float* Pf = (float*)&P[0][0];
  __syncthreads();
  if (whalf == 1) {
#pragma unroll
    for (int st = 0; st < 2; st++)
#pragma unroll
      for (int ci = 0; ci < 4; ci++)
        *(floatx4*)&Pf[(((wsub * 9 + st * 4 + ci) * 64) + lane) * 4] = o[st][ci];
    float2 rr; rr.x = rsum[0]; rr.y = rsum[1];
    *(float2*)&Pf[(((wsub * 9 + 8) * 64) + lane) * 4] = rr;
  }
  __syncthreads();
  if (whalf == 1) return;

#pragma unroll
  for (int st = 0; st < 2; st++)
#pragma unroll
    for (int ci = 0; ci < 4; ci++) {
      floatx4 p = *(const floatx4*)&Pf[(((wsub * 9 + st * 4 + ci) * 64) + lane) * 4];
      o[st][ci] += p;
    }
  {
    float2 pr = *(const float2*)&Pf[(((wsub * 9 + 8) * 64) + lane) * 4];
    rsum[0] += pr.x; rsum[1] += pr.y;
  }

  // ---- normalize + write ----
  // Full row sum for q-row st*16+c: reduce partials across the 4 hi-groups.
  float inv2[2];
#pragma unroll
  for (int st = 0; st < 2; st++) {
    float v = rsum[st];
    v += __shfl_xor(v, 16);
    v += __shfl_xor(v, 32);
    inv2[st] = 1.0f / v;
  }
  // redistribute: lane (c,q) stores rows q*4+r -> needs inv from lane c'=q*4+r
  const int sb = (lane & 48) + ((lane & 48) >> 2);
  float iv[2][4];
#pragma unroll
  for (int st = 0; st < 2; st++)
#pragma unroll
    for (int r = 0; r < 4; r++) iv[st][r] = __shfl(inv2[st], sb + r);

#pragma unroll
  for (int st = 0; st < 2; st++)
#pragma unroll
    for (int r = 0; r < 4; r++) {
      int n = rbase + st * 16 + q * 4 + r;
      size_t ob = ((size_t)((b << 10) + n)) * 512 + h * 64;
#pragma unroll
      for (int ci = 0; ci < 4; ci++)
        AO[ob + ci * 16 + c] = f2bf(o[st][ci][r] * iv[st][r]);
    }
}

// ---------------- launcher ----------------
extern "C" void kernel_launch(void* const* d_in, const int* in_sizes, int n_in,
                              void* d_out, int out_size, void* d_ws, size_t ws_size,
                              hipStream_t stream) {
  const float* query = (const float*)d_in[0];
  const float* key_  = (const float*)d_in[1];
  const float* value = (const float*)d_in[2];
  const float* dist  = (const float*)d_in[3];
  const int*   mask  = (const int*)d_in[4];
  const float* Wq = (const float*)d_in[5];
  const float* bq = (const float*)d_in[6];
  const float* Wk = (const float*)d_in[7];
  const float* bk = (const float*)d_in[8];
  const float* Wv = (const float*)d_in[9];
  const float* bv = (const float*)d_in[10];
  const float* Wo = (const float*)d_in[11];
  const float* bo = (const float*)d_in[12];

  char* ws = (char*)d_ws;
  size_t off = 0;
  auto alloc = [&](size_t bytes) -> char* {
    char* p = ws + off;
    off += (bytes + 255) & ~(size_t)255;
    return p;
  };
  const size_t NQKV = 8192ull * 512;
  unsigned short* wq16 = (unsigned short*)alloc(512ull * 512 * 2);
  unsigned short* wk16 = (unsigned short*)alloc(512ull * 512 * 2);
  unsigned short* wv16 = (unsigned short*)alloc(512ull * 512 * 2);
  unsigned short* wo16 = (unsigned short*)alloc(512ull * 512 * 2);
  unsigned short* Qh = (unsigned short*)alloc(NQKV * 2);
  unsigned short* Kh = (unsigned short*)alloc(NQKV * 2);
  unsigned short* Vt = (unsigned short*)alloc(NQKV * 2);
  unsigned short* AO = (unsigned short*)alloc(NQKV * 2);
  unsigned char*  codesP = (unsigned char*)alloc(8ull * 1024 * 1024);

  codes_kernel<<<9216, 256, 0, stream>>>(dist, mask, codesP, Wq, Wk, Wv, Wo,
                                         wq16, wk16, wv16, wo16);
  qkv_gemm<<<dim3(64, 4, 3), 256, 0, stream>>>(query, key_, value, wq16, wk16, wv16,
                                               bq, bk, bv, Qh, Kh, Vt);
  attn_kernel<<<dim3(16, 64), 256, 0, stream>>>(Qh, Kh, Vt, codesP, AO);
  out_gemm<<<dim3(128, 4), 256, 0, stream>>>(AO, wo16, bo, (float*)d_out);
}

// Round 8
// 277.397 us; speedup vs baseline: 1.0320x; 1.0320x over previous
//
#include <hip/hip_runtime.h>
#include <stdint.h>

// ---------------------------------------------------------------------------
// MultiHeadedAttention: B=8, N=1024, E=512, H=8, D_K=64
// bf16 MFMA pipeline. Round 11: attn XCD-aware swizzle — flat 1024-block grid
// remapped so XCD k owns batch k (8 heads x 16 q-blocks): K/V re-reads become
// L2 hits (FETCH 74->~32MB) and the R6 1-phase K prefetch now covers the load
// latency. qkv_gemm reverted to the R6 64x128 tile (R7's 128x128 regressed
// ~5-10us at this K=512 shape). codes+wcast merge kept. attn internals
// byte-identical to the measured-76.9us R6 kernel.
// ---------------------------------------------------------------------------

typedef __attribute__((ext_vector_type(8))) short short8;
typedef __attribute__((ext_vector_type(4))) float floatx4;

#define MFMA16(a, b, c) __builtin_amdgcn_mfma_f32_16x16x32_bf16((a), (b), (c), 0, 0, 0)

static __device__ __forceinline__ unsigned short f2bf(float f) {
  union { float f; unsigned u; } v; v.f = f;
  unsigned r = v.u + 0x7fffu + ((v.u >> 16) & 1u);   // RNE
  return (unsigned short)(r >> 16);
}

// async global->LDS 16B/lane. LDS dest is wave-uniform base + lane*16 (m104).
static __device__ __forceinline__ void gload_lds16(const void* g, void* l) {
  __builtin_amdgcn_global_load_lds((const __attribute__((address_space(1))) unsigned int*)g,
                                   (__attribute__((address_space(3))) unsigned int*)l,
                                   16, 0, 0);
}
// chunk swizzle for unpadded 32-elem-wide bf16 LDS tiles (GEMM staging).
static __device__ __forceinline__ int xsw(int row) { return (row & 3) ^ ((row >> 2) & 3); }

// ---------------- dist+mask -> codes  +  weight cast (merged) ----------------
// Blocks [0,8192): codes. Blocks [8192,9216): fp32->bf16 weight cast.
// codes layout matches the SWAPPED-QK^T attn epilogue: element
//   (q-row = rg*32 + st*16 + c, k-col = kt*128 + ci*16 + hi*4 + r)
// is held by attn lane = hi*16 + c at byte st*32 + ci*4 + r of its 64B block:
//   codesP[ (((b*32+rg)*8 + kt)*64 + lane)*64 + st*32 + ci*4 + r ]
__global__ void codes_kernel(const float* __restrict__ dist, const int* __restrict__ mask,
                             unsigned char* __restrict__ codesP,
                             const float* __restrict__ Wq, const float* __restrict__ Wk,
                             const float* __restrict__ Wv, const float* __restrict__ Wo,
                             unsigned short* __restrict__ o0, unsigned short* __restrict__ o1,
                             unsigned short* __restrict__ o2, unsigned short* __restrict__ o3) {
  if (blockIdx.x >= 8192) {   // ---- weight cast part ----
    int i = (blockIdx.x - 8192) * blockDim.x + threadIdx.x;   // 0..262143
    int w = i >> 16, loc = i & 65535;
    const float* s = (w == 0) ? Wq : (w == 1) ? Wk : (w == 2) ? Wv : Wo;
    unsigned short* d = (w == 0) ? o0 : (w == 1) ? o1 : (w == 2) ? o2 : o3;
    float4 v = ((const float4*)s)[loc];
    ushort4 o;
    o.x = f2bf(v.x); o.y = f2bf(v.y); o.z = f2bf(v.z); o.w = f2bf(v.w);
    ((ushort4*)d)[loc] = o;
    return;
  }
  int t = blockIdx.x * blockDim.x + threadIdx.x;   // over B*N*N/4
  int flat = t << 2;
  int b = flat >> 20;
  int rem = flat & ((1 << 20) - 1);
  int row = rem >> 10;
  int col0 = rem & 1023;                            // multiple of 4
  float4 d4 = ((const float4*)dist)[t];
  int4 m4 = ((const int4*)mask)[t];
  float dv[4] = {d4.x, d4.y, d4.z, d4.w};
  int mv[4] = {m4.x, m4.y, m4.z, m4.w};
  int rg = row >> 5;
  int st = (row >> 4) & 1;
  int c = row & 15;
  size_t rowbase = (size_t)(b * 32 + rg) * 32768;   // *8 kt *4096
  int kt = col0 >> 7;
  int colk = col0 & 127;
  int ci = colk >> 4;
  int hi = (colk >> 2) & 3;
  int lane = hi * 16 + c;
  unsigned pack = 0;
#pragma unroll
  for (int u = 0; u < 4; u++) {
    int col = col0 + u;
    float d = dv[u];
    int hmin = (d >= 0.2f) + (d >= 0.3f) + (d >= 0.4f) + (d >= 0.5f) +
               (d >= 0.6f) + (d >= 0.7f) + (d >= 0.8f) + (d >= 0.9f);
    unsigned cc = (unsigned)hmin;
    if (row == 0 || col == 0) cc = 0;
    if (mv[u] == 0) cc = 9;
    pack |= cc << (u * 8);
  }
  *(unsigned*)&codesP[rowbase + (size_t)kt * 4096 + lane * 64 + st * 32 + ci * 4] = pack;
}

// ---------------- fused QKV projection GEMM (64x128, R6-proven) ----------
// C[m][n] = sum_k A[m][k] * W[n][k] + bias[n];  M=8192, N=512, K=512.
// 64x128 tile, 4 waves. A fp32 (cast fused). z=0/1: [bh][n][d]; z=2: [bh][d][n].
__global__ __launch_bounds__(256) void qkv_gemm(
    const float* __restrict__ Aq, const float* __restrict__ Ak, const float* __restrict__ Av,
    const unsigned short* __restrict__ Wqp, const unsigned short* __restrict__ Wkp,
    const unsigned short* __restrict__ Wvp,
    const float* __restrict__ bq, const float* __restrict__ bk, const float* __restrict__ bv,
    unsigned short* __restrict__ Qh, unsigned short* __restrict__ Kh,
    unsigned short* __restrict__ Vt) {
  const int z = blockIdx.z;
  const float* A = (z == 0) ? Aq : (z == 1) ? Ak : Av;
  const unsigned short* W = (z == 0) ? Wqp : (z == 1) ? Wkp : Wvp;
  const float* bias = (z == 0) ? bq : (z == 1) ? bk : bv;
  unsigned short* O = (z == 0) ? Qh : (z == 1) ? Kh : Vt;

  __shared__ __align__(16) short As[64 * 40];
  __shared__ __align__(16) short Bs[128 * 32];
  const int tid = threadIdx.x;
  const int lane = tid & 63;
  const int wave = tid >> 6;
  const int c = lane & 15;
  const int q = lane >> 4;
  const int m0 = blockIdx.x * 64;
  const int n0 = blockIdx.y * 128;
  const int wr = (wave >> 1) * 32;
  const int wc = (wave & 1) * 64;

  floatx4 acc[2][4];
#pragma unroll
  for (int i = 0; i < 2; i++)
#pragma unroll
    for (int j = 0; j < 4; j++) acc[i][j] = (floatx4)(0.0f);

  const int arow = tid >> 2, ach = tid & 3;
  const float* Ab = A + (size_t)(m0 + arow) * 512 + ach * 8;

  for (int k0 = 0; k0 < 512; k0 += 32) {
    __syncthreads();
#pragma unroll
    for (int it = 0; it < 2; it++) {
      int slot = wave * 128 + it * 64 + lane;
      int brow = slot >> 2, bch = slot & 3;
      int g = bch ^ xsw(brow);
      gload_lds16(W + (size_t)(n0 + brow) * 512 + k0 + g * 8,
                  &Bs[(size_t)(wave * 128 + it * 64) * 8]);
    }
    float4 a0 = *(const float4*)(Ab + k0);
    float4 a1 = *(const float4*)(Ab + k0 + 4);
    short8 av;
    av[0] = (short)f2bf(a0.x); av[1] = (short)f2bf(a0.y);
    av[2] = (short)f2bf(a0.z); av[3] = (short)f2bf(a0.w);
    av[4] = (short)f2bf(a1.x); av[5] = (short)f2bf(a1.y);
    av[6] = (short)f2bf(a1.z); av[7] = (short)f2bf(a1.w);
    *(short8*)(&As[arow * 40 + ach * 8]) = av;
    __syncthreads();

    short8 af[2], bfv[4];
#pragma unroll
    for (int i = 0; i < 2; i++)
      af[i] = *(const short8*)(&As[(wr + i * 16 + c) * 40 + q * 8]);
#pragma unroll
    for (int j = 0; j < 4; j++) {
      int row = wc + j * 16 + c;
      bfv[j] = *(const short8*)(&Bs[row * 32 + (q ^ xsw(row)) * 8]);
    }
#pragma unroll
    for (int i = 0; i < 2; i++)
#pragma unroll
      for (int j = 0; j < 4; j++)
        acc[i][j] = MFMA16(af[i], bfv[j], acc[i][j]);
  }

#pragma unroll
  for (int i = 0; i < 2; i++) {
    int gm0 = m0 + wr + i * 16 + q * 4;
#pragma unroll
    for (int j = 0; j < 4; j++) {
      int gn = n0 + wc + j * 16 + c;
      float bb = bias[gn];
      int h = gn >> 6, d = gn & 63;
      if (z == 2) {
        int b = gm0 >> 10, n = gm0 & 1023;
        ushort4 pk;
#pragma unroll
        for (int r = 0; r < 4; r++) pk[r] = f2bf(acc[i][j][r] + bb);
        *(ushort4*)(&Vt[(((size_t)(b * 8 + h) * 64 + d) << 10) + n]) = pk;  // [bh][d][n]
      } else {
#pragma unroll
        for (int r = 0; r < 4; r++) {
          int m = gm0 + r;
          int b = m >> 10, n = m & 1023;
          O[((((size_t)(b * 8 + h)) << 10) + n) * 64 + d] = f2bf(acc[i][j][r] + bb);
        }
      }
    }
  }
}

// ---------------- output projection GEMM (bf16 A, fp32 out) ----------------
__global__ __launch_bounds__(256) void out_gemm(const unsigned short* __restrict__ A,
                                                const unsigned short* __restrict__ W,
                                                const float* __restrict__ bias,
                                                float* __restrict__ Out) {
  __shared__ __align__(16) short As[64 * 32];
  __shared__ __align__(16) short Bs[128 * 32];
  const int tid = threadIdx.x;
  const int lane = tid & 63;
  const int wave = tid >> 6;
  const int c = lane & 15;
  const int q = lane >> 4;
  const int m0 = blockIdx.x * 64;
  const int n0 = blockIdx.y * 128;
  const int wr = (wave >> 1) * 32;
  const int wc = (wave & 1) * 64;

  floatx4 acc[2][4];
#pragma unroll
  for (int i = 0; i < 2; i++)
#pragma unroll
    for (int j = 0; j < 4; j++) acc[i][j] = (floatx4)(0.0f);

  for (int k0 = 0; k0 < 512; k0 += 32) {
    __syncthreads();
    {
      int slot = wave * 64 + lane;
      int arow = slot >> 2, ach = slot & 3;
      int g = ach ^ xsw(arow);
      gload_lds16(A + (size_t)(m0 + arow) * 512 + k0 + g * 8, &As[(size_t)(wave * 64) * 8]);
    }
#pragma unroll
    for (int it = 0; it < 2; it++) {
      int slot = wave * 128 + it * 64 + lane;
      int brow = slot >> 2, bch = slot & 3;
      int g = bch ^ xsw(brow);
      gload_lds16(W + (size_t)(n0 + brow) * 512 + k0 + g * 8,
                  &Bs[(size_t)(wave * 128 + it * 64) * 8]);
    }
    __syncthreads();

    short8 af[2], bfv[4];
#pragma unroll
    for (int i = 0; i < 2; i++) {
      int row = wr + i * 16 + c;
      af[i] = *(const short8*)(&As[row * 32 + (q ^ xsw(row)) * 8]);
    }
#pragma unroll
    for (int j = 0; j < 4; j++) {
      int row = wc + j * 16 + c;
      bfv[j] = *(const short8*)(&Bs[row * 32 + (q ^ xsw(row)) * 8]);
    }
#pragma unroll
    for (int i = 0; i < 2; i++)
#pragma unroll
      for (int j = 0; j < 4; j++)
        acc[i][j] = MFMA16(af[i], bfv[j], acc[i][j]);
  }

#pragma unroll
  for (int i = 0; i < 2; i++) {
    int gm0 = m0 + wr + i * 16 + q * 4;
#pragma unroll
    for (int j = 0; j < 4; j++) {
      int gn = n0 + wc + j * 16 + c;
      float bb = bias[gn];
#pragma unroll
      for (int r = 0; r < 4; r++)
        Out[(size_t)(gm0 + r) * 512 + gn] = acc[i][j][r] + bb;
    }
  }
}

// ---------------- software-pipelined flash attention (kt-split) ----------
// Internals identical to R6 (measured 76.9 us). NEW: flat 1024-block grid
// with XCD-aware swizzle: swz = (bid&7)*128 + bid>>3 -> bh = swz>>4,
// gx = swz&15. Under round-robin dispatch, XCD k owns bh [8k,8k+8) = batch
// k's 8 heads: Q+K+V (3MB) + that batch's codes (1MB) fit its 4MB L2, so
// K/V re-reads (16 q-blocks/head) hit L2 and the 1-phase K prefetch covers
// the latency. Bijective mapping; perf-only assumption (G16-safe).
__global__ __launch_bounds__(256, 3) void attn_kernel(const unsigned short* __restrict__ Qh,
                                                      const unsigned short* __restrict__ Kh,
                                                      const unsigned short* __restrict__ Vt,
                                                      const unsigned char* __restrict__ codesP,
                                                      unsigned short* __restrict__ AO) {
  __shared__ __align__(16) unsigned short P[4][32 * 132];   // 33 KB, wave-private regions
  const int tid = threadIdx.x;
  const int lane = tid & 63;
  const int wave = tid >> 6;
  const int wsub = wave & 1;     // which 32-row sub-block
  const int whalf = wave >> 1;   // which kt half
  const int c = lane & 15;
  const int q = lane >> 4;
  const int bid = blockIdx.x;
  const int swz = ((bid & 7) << 7) | (bid >> 3);   // XCD-contiguous remap
  const int bh = swz >> 4;
  const int gx = swz & 15;
  const int b = bh >> 3;
  const int h = bh & 7;
  const size_t base = (size_t)bh << 16;
  const int rbase = gx * 64 + wsub * 32;
  const int rg = rbase >> 5;
  unsigned short* Pw = &P[wave][0];

  // Q A-fragments for both 16-row stripes, held all kernel
  short8 aq[2][2];
#pragma unroll
  for (int st = 0; st < 2; st++)
#pragma unroll
    for (int kk = 0; kk < 2; kk++)
      aq[st][kk] = *(const short8*)(Qh + base + (size_t)(rbase + st * 16 + c) * 64 + kk * 32 + q * 8);

  const unsigned char* cbt = codesP + (size_t)(b * 32 + rg) * 32768 + lane * 64;
  const unsigned short* Kb = Kh + base;
  const unsigned short* Vb = Vt + base;

  float rsum[2] = {0.0f, 0.0f};
  floatx4 o[2][4];
#pragma unroll
  for (int st = 0; st < 2; st++)
#pragma unroll
    for (int ci = 0; ci < 4; ci++) o[st][ci] = (floatx4)(0.0f);

  // ---- prologue: prefetch K fragments for phase 0 (kt=whalf*4, j=0) ----
  short8 bk00, bk01, bk10, bk11;   // [u][kk], u: ci=2j+u
  {
    const unsigned short* Kt0 = Kb + (size_t)(whalf * 4) * 8192;
    bk00 = *(const short8*)(Kt0 + (size_t)(0 * 16 + c) * 64 + 0 * 32 + q * 8);
    bk01 = *(const short8*)(Kt0 + (size_t)(0 * 16 + c) * 64 + 1 * 32 + q * 8);
    bk10 = *(const short8*)(Kt0 + (size_t)(1 * 16 + c) * 64 + 0 * 32 + q * 8);
    bk11 = *(const short8*)(Kt0 + (size_t)(1 * 16 + c) * 64 + 1 * 32 + q * 8);
  }

#pragma unroll
  for (int ph = 0; ph < 16; ph++) {
    const int kt = whalf * 4 + (ph >> 2);
    const int j = ph & 3;
    const unsigned char* cp = cbt + (size_t)kt * 4096;

    // ---- top: V loads for THIS phase (consumed by PV at the bottom) ----
    short8 vv0 = *(const short8*)(Vb + (size_t)(0 * 16 + c) * 1024 + kt * 128 + j * 32 + q * 8);
    short8 vv1 = *(const short8*)(Vb + (size_t)(1 * 16 + c) * 1024 + kt * 128 + j * 32 + q * 8);
    short8 vv2 = *(const short8*)(Vb + (size_t)(2 * 16 + c) * 1024 + kt * 128 + j * 32 + q * 8);
    short8 vv3 = *(const short8*)(Vb + (size_t)(3 * 16 + c) * 1024 + kt * 128 + j * 32 + q * 8);
    uint2 cw0 = *(const uint2*)(cp + j * 8);        // st=0 codes
    uint2 cw1 = *(const uint2*)(cp + 32 + j * 8);   // st=1 codes

    // ---- swapped QK^T on prefetched K: lane holds S[q=c][k] ----
    floatx4 s2[2][2];
    s2[0][0] = (floatx4)(0.0f); s2[0][1] = (floatx4)(0.0f);
    s2[1][0] = (floatx4)(0.0f); s2[1][1] = (floatx4)(0.0f);
    s2[0][0] = MFMA16(bk00, aq[0][0], s2[0][0]);
    s2[1][0] = MFMA16(bk00, aq[1][0], s2[1][0]);
    s2[0][0] = MFMA16(bk01, aq[0][1], s2[0][0]);
    s2[1][0] = MFMA16(bk01, aq[1][1], s2[1][0]);
    s2[0][1] = MFMA16(bk10, aq[0][0], s2[0][1]);
    s2[1][1] = MFMA16(bk10, aq[1][0], s2[1][1]);
    s2[0][1] = MFMA16(bk11, aq[0][1], s2[0][1]);
    s2[1][1] = MFMA16(bk11, aq[1][1], s2[1][1]);

    // ---- prefetch K for the NEXT phase (WAR on bk regs is issue-safe) ----
    if (ph < 15) {
      const int phn = ph + 1;
      const int ktn = whalf * 4 + (phn >> 2);
      const int jn = phn & 3;
      const unsigned short* Ktn = Kb + (size_t)ktn * 8192;
      bk00 = *(const short8*)(Ktn + (size_t)((2 * jn + 0) * 16 + c) * 64 + 0 * 32 + q * 8);
      bk01 = *(const short8*)(Ktn + (size_t)((2 * jn + 0) * 16 + c) * 64 + 1 * 32 + q * 8);
      bk10 = *(const short8*)(Ktn + (size_t)((2 * jn + 1) * 16 + c) * 64 + 0 * 32 + q * 8);
      bk11 = *(const short8*)(Ktn + (size_t)((2 * jn + 1) * 16 + c) * 64 + 1 * 32 + q * 8);
    }

    // ---- exp -> cvt_pk -> b64 P write + scalar row sums ----
#pragma unroll
    for (int st = 0; st < 2; st++) {
#pragma unroll
      for (int u = 0; u < 2; u++) {
        unsigned w = st ? (u ? cw1.y : cw1.x) : (u ? cw0.y : cw0.x);
        float ev[4];
#pragma unroll
        for (int r = 0; r < 4; r++) {
          int code = (w >> (r * 8)) & 0xff;
          float ee = (h >= code) ? exp2f(s2[st][u][r] * 0.1803368801111362f) : 0.0f;
          rsum[st] += ee;
          ev[r] = ee;
        }
        unsigned p0, p1;
        asm("v_cvt_pk_bf16_f32 %0, %1, %2" : "=v"(p0) : "v"(ev[0]), "v"(ev[1]));
        asm("v_cvt_pk_bf16_f32 %0, %1, %2" : "=v"(p1) : "v"(ev[2]), "v"(ev[3]));
        uint2 pk; pk.x = p0; pk.y = p1;
        *(uint2*)(&Pw[(st * 16 + c) * 132 + (2 * j + u) * 16 + q * 4]) = pk;
      }
    }

    __builtin_amdgcn_sched_barrier(0);   // phase waist: write side || read side

    // ---- PV: read back own P (lgkm) x resident V frags ----
    short8 ap0 = *(const short8*)(&Pw[(size_t)c * 132 + j * 32 + q * 8]);
    short8 ap1 = *(const short8*)(&Pw[(size_t)(16 + c) * 132 + j * 32 + q * 8]);
    o[0][0] = MFMA16(ap0, vv0, o[0][0]);
    o[1][0] = MFMA16(ap1, vv0, o[1][0]);
    o[0][1] = MFMA16(ap0, vv1, o[0][1]);
    o[1][1] = MFMA16(ap1, vv1, o[1][1]);
    o[0][2] = MFMA16(ap0, vv2, o[0][2]);
    o[1][2] = MFMA16(ap1, vv2, o[1][2]);
    o[0][3] = MFMA16(ap0, vv3, o[0][3]);
    o[1][3] = MFMA16(ap1, vv3, o[1][3]);
  }

  // ---- merge kt-half partials: waves 2,3 -> LDS, waves 0,1 accumulate ----
  // chunks 0..7 = o[st][ci] (float4), chunk 8 = rsum[0..1] (float2). 18 KB.
  float* Pf = (float*)&P[0][0];
  __syncthreads();
  if (whalf == 1) {
#pragma unroll
    for (int st = 0; st < 2; st++)
#pragma unroll
      for (int ci = 0; ci < 4; ci++)
        *(floatx4*)&Pf[(((wsub * 9 + st * 4 + ci) * 64) + lane) * 4] = o[st][ci];
    float2 rr; rr.x = rsum[0]; rr.y = rsum[1];
    *(float2*)&Pf[(((wsub * 9 + 8) * 64) + lane) * 4] = rr;
  }
  __syncthreads();
  if (whalf == 1) return;

#pragma unroll
  for (int st = 0; st < 2; st++)
#pragma unroll
    for (int ci = 0; ci < 4; ci++) {
      floatx4 p = *(const floatx4*)&Pf[(((wsub * 9 + st * 4 + ci) * 64) + lane) * 4];
      o[st][ci] += p;
    }
  {
    float2 pr = *(const float2*)&Pf[(((wsub * 9 + 8) * 64) + lane) * 4];
    rsum[0] += pr.x; rsum[1] += pr.y;
  }

  // ---- normalize + write ----
  // Full row sum for q-row st*16+c: reduce partials across the 4 hi-groups.
  float inv2[2];
#pragma unroll
  for (int st = 0; st < 2; st++) {
    float v = rsum[st];
    v += __shfl_xor(v, 16);
    v += __shfl_xor(v, 32);
    inv2[st] = 1.0f / v;
  }
  // redistribute: lane (c,q) stores rows q*4+r -> needs inv from lane c'=q*4+r
  const int sb = (lane & 48) + ((lane & 48) >> 2);
  float iv[2][4];
#pragma unroll
  for (int st = 0; st < 2; st++)
#pragma unroll
    for (int r = 0; r < 4; r++) iv[st][r] = __shfl(inv2[st], sb + r);

#pragma unroll
  for (int st = 0; st < 2; st++)
#pragma unroll
    for (int r = 0; r < 4; r++) {
      int n = rbase + st * 16 + q * 4 + r;
      size_t ob = ((size_t)((b << 10) + n)) * 512 + h * 64;
#pragma unroll
      for (int ci = 0; ci < 4; ci++)
        AO[ob + ci * 16 + c] = f2bf(o[st][ci][r] * iv[st][r]);
    }
}

// ---------------- launcher ----------------
extern "C" void kernel_launch(void* const* d_in, const int* in_sizes, int n_in,
                              void* d_out, int out_size, void* d_ws, size_t ws_size,
                              hipStream_t stream) {
  const float* query = (const float*)d_in[0];
  const float* key_  = (const float*)d_in[1];
  const float* value = (const float*)d_in[2];
  const float* dist  = (const float*)d_in[3];
  const int*   mask  = (const int*)d_in[4];
  const float* Wq = (const float*)d_in[5];
  const float* bq = (const float*)d_in[6];
  const float* Wk = (const float*)d_in[7];
  const float* bk = (const float*)d_in[8];
  const float* Wv = (const float*)d_in[9];
  const float* bv = (const float*)d_in[10];
  const float* Wo = (const float*)d_in[11];
  const float* bo = (const float*)d_in[12];

  char* ws = (char*)d_ws;
  size_t off = 0;
  auto alloc = [&](size_t bytes) -> char* {
    char* p = ws + off;
    off += (bytes + 255) & ~(size_t)255;
    return p;
  };
  const size_t NQKV = 8192ull * 512;
  unsigned short* wq16 = (unsigned short*)alloc(512ull * 512 * 2);
  unsigned short* wk16 = (unsigned short*)alloc(512ull * 512 * 2);
  unsigned short* wv16 = (unsigned short*)alloc(512ull * 512 * 2);
  unsigned short* wo16 = (unsigned short*)alloc(512ull * 512 * 2);
  unsigned short* Qh = (unsigned short*)alloc(NQKV * 2);
  unsigned short* Kh = (unsigned short*)alloc(NQKV * 2);
  unsigned short* Vt = (unsigned short*)alloc(NQKV * 2);
  unsigned short* AO = (unsigned short*)alloc(NQKV * 2);
  unsigned char*  codesP = (unsigned char*)alloc(8ull * 1024 * 1024);

  codes_kernel<<<9216, 256, 0, stream>>>(dist, mask, codesP, Wq, Wk, Wv, Wo,
                                         wq16, wk16, wv16, wo16);
  qkv_gemm<<<dim3(128, 4, 3), 256, 0, stream>>>(query, key_, value, wq16, wk16, wv16,
                                                bq, bk, bv, Qh, Kh, Vt);
  attn_kernel<<<1024, 256, 0, stream>>>(Qh, Kh, Vt, codesP, AO);
  out_gemm<<<dim3(128, 4), 256, 0, stream>>>(AO, wo16, bo, (float*)d_out);
}

// Round 9
// 274.253 us; speedup vs baseline: 1.0438x; 1.0115x over previous
//
#include <hip/hip_runtime.h>
#include <stdint.h>

// ---------------------------------------------------------------------------
// MultiHeadedAttention: B=8, N=1024, E=512, H=8, D_K=64
// bf16 MFMA pipeline. Round 12: non-attn pipeline fixes.
//  (1) codes written via LDS transpose: one block per (b,rg,kt) 4KB tile,
//      scattered byte layout built in LDS, flushed as coalesced uint4 —
//      kills the 16x partial-line write amplification of the old path.
//  (2) Q/K/V inputs pre-cast to bf16 (same RNE as old in-loop cast ->
//      bit-identical results).
//  (3) qkv_gemm rebuilt on the proven out_gemm structure (all-bf16 operands,
//      gload_lds16 A staging, no in-loop casts).
// attn_kernel byte-identical to R8 (77.5us control, FETCH 16.6MB tripwire).
// ---------------------------------------------------------------------------

typedef __attribute__((ext_vector_type(8))) short short8;
typedef __attribute__((ext_vector_type(4))) float floatx4;

#define MFMA16(a, b, c) __builtin_amdgcn_mfma_f32_16x16x32_bf16((a), (b), (c), 0, 0, 0)

static __device__ __forceinline__ unsigned short f2bf(float f) {
  union { float f; unsigned u; } v; v.f = f;
  unsigned r = v.u + 0x7fffu + ((v.u >> 16) & 1u);   // RNE
  return (unsigned short)(r >> 16);
}

// async global->LDS 16B/lane. LDS dest is wave-uniform base + lane*16 (m104).
static __device__ __forceinline__ void gload_lds16(const void* g, void* l) {
  __builtin_amdgcn_global_load_lds((const __attribute__((address_space(1))) unsigned int*)g,
                                   (__attribute__((address_space(3))) unsigned int*)l,
                                   16, 0, 0);
}
// chunk swizzle for unpadded 32-elem-wide bf16 LDS tiles (GEMM staging).
static __device__ __forceinline__ int xsw(int row) { return (row & 3) ^ ((row >> 2) & 3); }

// ---------------- prep: codes (LDS-transposed) + all bf16 casts ----------
// Blocks [0,2048): codes, one block per (b,rg,kt) = one 4KB output tile.
// Blocks [2048,3072): weight cast (4 x 512x512 fp32 -> bf16).
// Blocks [3072,9216): Q/K/V input cast (3 x 8192x512 fp32 -> bf16).
// codes layout (matches swapped-QK^T attn epilogue): element
//   (q-row = rg*32 + st*16 + c, k-col = kt*128 + ci*16 + hi*4 + r)
// at byte (hi*16+c)*64 + st*32 + ci*4 + r of tile (b*32+rg)*8+kt.
__global__ void prep_kernel(const float* __restrict__ dist, const int* __restrict__ mask,
                            unsigned char* __restrict__ codesP,
                            const float* __restrict__ Wq, const float* __restrict__ Wk,
                            const float* __restrict__ Wv, const float* __restrict__ Wo,
                            unsigned short* __restrict__ o0, unsigned short* __restrict__ o1,
                            unsigned short* __restrict__ o2, unsigned short* __restrict__ o3,
                            const float* __restrict__ Qf, const float* __restrict__ Kf,
                            const float* __restrict__ Vf,
                            unsigned short* __restrict__ Qb, unsigned short* __restrict__ Kb,
                            unsigned short* __restrict__ Vb) {
  const int tid = threadIdx.x;
  const unsigned bx = blockIdx.x;
  if (bx >= 3072) {              // ---- Q/K/V input cast: 8 floats/thread ----
    int j = bx - 3072;           // 0..6143
    int arr = j >> 11;           // 0..2
    const float* s = (arr == 0) ? Qf : (arr == 1) ? Kf : Vf;
    unsigned short* d = (arr == 0) ? Qb : (arr == 1) ? Kb : Vb;
    int idx = (j & 2047) * 256 + tid;       // 0..524287, 8 floats each
    float4 v0 = ((const float4*)s)[idx * 2];
    float4 v1 = ((const float4*)s)[idx * 2 + 1];
    short8 o;
    o[0] = (short)f2bf(v0.x); o[1] = (short)f2bf(v0.y);
    o[2] = (short)f2bf(v0.z); o[3] = (short)f2bf(v0.w);
    o[4] = (short)f2bf(v1.x); o[5] = (short)f2bf(v1.y);
    o[6] = (short)f2bf(v1.z); o[7] = (short)f2bf(v1.w);
    *(short8*)(d + (size_t)idx * 8) = o;
    return;
  }
  if (bx >= 2048) {              // ---- weight cast ----
    int i = (bx - 2048) * 256 + tid;        // 0..262143
    int w = i >> 16, loc = i & 65535;
    const float* s = (w == 0) ? Wq : (w == 1) ? Wk : (w == 2) ? Wv : Wo;
    unsigned short* d = (w == 0) ? o0 : (w == 1) ? o1 : (w == 2) ? o2 : o3;
    float4 v = ((const float4*)s)[loc];
    ushort4 o;
    o.x = f2bf(v.x); o.y = f2bf(v.y); o.z = f2bf(v.z); o.w = f2bf(v.w);
    ((ushort4*)d)[loc] = o;
    return;
  }
  // ---- codes: block bc = (b*32+rg)*8 + kt ----
  __shared__ __align__(16) unsigned char cbuf[4096];
  const int bc = bx;
  const int b = bc >> 8;
  const int rg = (bc >> 3) & 31;
  const int kt = bc & 7;
  const int row_local = tid >> 3;          // 0..31
  const int colseg = (tid & 7) * 16;       // 0..112
  const int row = rg * 32 + row_local;
  const int st = row_local >> 4;
  const int c = row_local & 15;
  const int ci = tid & 7;
  const size_t ibase = ((size_t)b << 20) + (size_t)row * 1024 + kt * 128 + colseg;
  float4 d4[4]; int4 m4[4];
#pragma unroll
  for (int g = 0; g < 4; g++) {
    d4[g] = ((const float4*)(dist + ibase))[g];
    m4[g] = ((const int4*)(mask + ibase))[g];
  }
#pragma unroll
  for (int hi = 0; hi < 4; hi++) {
    float dvv[4] = {d4[hi].x, d4[hi].y, d4[hi].z, d4[hi].w};
    int mvv[4] = {m4[hi].x, m4[hi].y, m4[hi].z, m4[hi].w};
    unsigned pack = 0;
#pragma unroll
    for (int r = 0; r < 4; r++) {
      int col = kt * 128 + colseg + hi * 4 + r;
      float d = dvv[r];
      int hmin = (d >= 0.2f) + (d >= 0.3f) + (d >= 0.4f) + (d >= 0.5f) +
                 (d >= 0.6f) + (d >= 0.7f) + (d >= 0.8f) + (d >= 0.9f);
      unsigned cc = (unsigned)hmin;
      if (row == 0 || col == 0) cc = 0;
      if (mvv[r] == 0) cc = 9;
      pack |= cc << (r * 8);
    }
    *(unsigned*)&cbuf[(hi * 16 + c) * 64 + st * 32 + ci * 4] = pack;
  }
  __syncthreads();
  *(uint4*)&codesP[(size_t)bc * 4096 + tid * 16] = *(const uint4*)&cbuf[tid * 16];
}

// ---------------- fused QKV projection GEMM (all-bf16, out_gemm structure) --
// C[m][n] = sum_k A[m][k] * W[n][k] + bias[n];  M=8192, N=512, K=512.
// 64x128 tile, 4 waves, A bf16 via gload_lds16. z=0/1: [bh][n][d]; z=2: [bh][d][n].
__global__ __launch_bounds__(256) void qkv_gemm(
    const unsigned short* __restrict__ Aq, const unsigned short* __restrict__ Ak,
    const unsigned short* __restrict__ Av,
    const unsigned short* __restrict__ Wqp, const unsigned short* __restrict__ Wkp,
    const unsigned short* __restrict__ Wvp,
    const float* __restrict__ bq, const float* __restrict__ bk, const float* __restrict__ bv,
    unsigned short* __restrict__ Qh, unsigned short* __restrict__ Kh,
    unsigned short* __restrict__ Vt) {
  const int z = blockIdx.z;
  const unsigned short* A = (z == 0) ? Aq : (z == 1) ? Ak : Av;
  const unsigned short* W = (z == 0) ? Wqp : (z == 1) ? Wkp : Wvp;
  const float* bias = (z == 0) ? bq : (z == 1) ? bk : bv;
  unsigned short* O = (z == 0) ? Qh : (z == 1) ? Kh : Vt;

  __shared__ __align__(16) short As[64 * 32];
  __shared__ __align__(16) short Bs[128 * 32];
  const int tid = threadIdx.x;
  const int lane = tid & 63;
  const int wave = tid >> 6;
  const int c = lane & 15;
  const int q = lane >> 4;
  const int m0 = blockIdx.x * 64;
  const int n0 = blockIdx.y * 128;
  const int wr = (wave >> 1) * 32;
  const int wc = (wave & 1) * 64;

  floatx4 acc[2][4];
#pragma unroll
  for (int i = 0; i < 2; i++)
#pragma unroll
    for (int j = 0; j < 4; j++) acc[i][j] = (floatx4)(0.0f);

  for (int k0 = 0; k0 < 512; k0 += 32) {
    __syncthreads();
    {
      int slot = wave * 64 + lane;
      int arow = slot >> 2, ach = slot & 3;
      int g = ach ^ xsw(arow);
      gload_lds16(A + (size_t)(m0 + arow) * 512 + k0 + g * 8, &As[(size_t)(wave * 64) * 8]);
    }
#pragma unroll
    for (int it = 0; it < 2; it++) {
      int slot = wave * 128 + it * 64 + lane;
      int brow = slot >> 2, bch = slot & 3;
      int g = bch ^ xsw(brow);
      gload_lds16(W + (size_t)(n0 + brow) * 512 + k0 + g * 8,
                  &Bs[(size_t)(wave * 128 + it * 64) * 8]);
    }
    __syncthreads();

    short8 af[2], bfv[4];
#pragma unroll
    for (int i = 0; i < 2; i++) {
      int row = wr + i * 16 + c;
      af[i] = *(const short8*)(&As[row * 32 + (q ^ xsw(row)) * 8]);
    }
#pragma unroll
    for (int j = 0; j < 4; j++) {
      int row = wc + j * 16 + c;
      bfv[j] = *(const short8*)(&Bs[row * 32 + (q ^ xsw(row)) * 8]);
    }
#pragma unroll
    for (int i = 0; i < 2; i++)
#pragma unroll
      for (int j = 0; j < 4; j++)
        acc[i][j] = MFMA16(af[i], bfv[j], acc[i][j]);
  }

#pragma unroll
  for (int i = 0; i < 2; i++) {
    int gm0 = m0 + wr + i * 16 + q * 4;
#pragma unroll
    for (int j = 0; j < 4; j++) {
      int gn = n0 + wc + j * 16 + c;
      float bb = bias[gn];
      int h = gn >> 6, d = gn & 63;
      if (z == 2) {
        int b = gm0 >> 10, n = gm0 & 1023;
        ushort4 pk;
#pragma unroll
        for (int r = 0; r < 4; r++) pk[r] = f2bf(acc[i][j][r] + bb);
        *(ushort4*)(&Vt[(((size_t)(b * 8 + h) * 64 + d) << 10) + n]) = pk;  // [bh][d][n]
      } else {
#pragma unroll
        for (int r = 0; r < 4; r++) {
          int m = gm0 + r;
          int b = m >> 10, n = m & 1023;
          O[((((size_t)(b * 8 + h)) << 10) + n) * 64 + d] = f2bf(acc[i][j][r] + bb);
        }
      }
    }
  }
}

// ---------------- output projection GEMM (bf16 A, fp32 out) ----------------
__global__ __launch_bounds__(256) void out_gemm(const unsigned short* __restrict__ A,
                                                const unsigned short* __restrict__ W,
                                                const float* __restrict__ bias,
                                                float* __restrict__ Out) {
  __shared__ __align__(16) short As[64 * 32];
  __shared__ __align__(16) short Bs[128 * 32];
  const int tid = threadIdx.x;
  const int lane = tid & 63;
  const int wave = tid >> 6;
  const int c = lane & 15;
  const int q = lane >> 4;
  const int m0 = blockIdx.x * 64;
  const int n0 = blockIdx.y * 128;
  const int wr = (wave >> 1) * 32;
  const int wc = (wave & 1) * 64;

  floatx4 acc[2][4];
#pragma unroll
  for (int i = 0; i < 2; i++)
#pragma unroll
    for (int j = 0; j < 4; j++) acc[i][j] = (floatx4)(0.0f);

  for (int k0 = 0; k0 < 512; k0 += 32) {
    __syncthreads();
    {
      int slot = wave * 64 + lane;
      int arow = slot >> 2, ach = slot & 3;
      int g = ach ^ xsw(arow);
      gload_lds16(A + (size_t)(m0 + arow) * 512 + k0 + g * 8, &As[(size_t)(wave * 64) * 8]);
    }
#pragma unroll
    for (int it = 0; it < 2; it++) {
      int slot = wave * 128 + it * 64 + lane;
      int brow = slot >> 2, bch = slot & 3;
      int g = bch ^ xsw(brow);
      gload_lds16(W + (size_t)(n0 + brow) * 512 + k0 + g * 8,
                  &Bs[(size_t)(wave * 128 + it * 64) * 8]);
    }
    __syncthreads();

    short8 af[2], bfv[4];
#pragma unroll
    for (int i = 0; i < 2; i++) {
      int row = wr + i * 16 + c;
      af[i] = *(const short8*)(&As[row * 32 + (q ^ xsw(row)) * 8]);
    }
#pragma unroll
    for (int j = 0; j < 4; j++) {
      int row = wc + j * 16 + c;
      bfv[j] = *(const short8*)(&Bs[row * 32 + (q ^ xsw(row)) * 8]);
    }
#pragma unroll
    for (int i = 0; i < 2; i++)
#pragma unroll
      for (int j = 0; j < 4; j++)
        acc[i][j] = MFMA16(af[i], bfv[j], acc[i][j]);
  }

#pragma unroll
  for (int i = 0; i < 2; i++) {
    int gm0 = m0 + wr + i * 16 + q * 4;
#pragma unroll
    for (int j = 0; j < 4; j++) {
      int gn = n0 + wc + j * 16 + c;
      float bb = bias[gn];
#pragma unroll
      for (int r = 0; r < 4; r++)
        Out[(size_t)(gm0 + r) * 512 + gn] = acc[i][j][r] + bb;
    }
  }
}

// ---------------- software-pipelined flash attention (kt-split) ----------
// Byte-identical to R8 (77.5us, FETCH 16.6MB): XCD swizzle + phase pipeline.
__global__ __launch_bounds__(256, 3) void attn_kernel(const unsigned short* __restrict__ Qh,
                                                      const unsigned short* __restrict__ Kh,
                                                      const unsigned short* __restrict__ Vt,
                                                      const unsigned char* __restrict__ codesP,
                                                      unsigned short* __restrict__ AO) {
  __shared__ __align__(16) unsigned short P[4][32 * 132];   // 33 KB, wave-private regions
  const int tid = threadIdx.x;
  const int lane = tid & 63;
  const int wave = tid >> 6;
  const int wsub = wave & 1;     // which 32-row sub-block
  const int whalf = wave >> 1;   // which kt half
  const int c = lane & 15;
  const int q = lane >> 4;
  const int bid = blockIdx.x;
  const int swz = ((bid & 7) << 7) | (bid >> 3);   // XCD-contiguous remap
  const int bh = swz >> 4;
  const int gx = swz & 15;
  const int b = bh >> 3;
  const int h = bh & 7;
  const size_t base = (size_t)bh << 16;
  const int rbase = gx * 64 + wsub * 32;
  const int rg = rbase >> 5;
  unsigned short* Pw = &P[wave][0];

  // Q A-fragments for both 16-row stripes, held all kernel
  short8 aq[2][2];
#pragma unroll
  for (int st = 0; st < 2; st++)
#pragma unroll
    for (int kk = 0; kk < 2; kk++)
      aq[st][kk] = *(const short8*)(Qh + base + (size_t)(rbase + st * 16 + c) * 64 + kk * 32 + q * 8);

  const unsigned char* cbt = codesP + (size_t)(b * 32 + rg) * 32768 + lane * 64;
  const unsigned short* Kb = Kh + base;
  const unsigned short* Vb = Vt + base;

  float rsum[2] = {0.0f, 0.0f};
  floatx4 o[2][4];
#pragma unroll
  for (int st = 0; st < 2; st++)
#pragma unroll
    for (int ci = 0; ci < 4; ci++) o[st][ci] = (floatx4)(0.0f);

  // ---- prologue: prefetch K fragments for phase 0 (kt=whalf*4, j=0) ----
  short8 bk00, bk01, bk10, bk11;   // [u][kk], u: ci=2j+u
  {
    const unsigned short* Kt0 = Kb + (size_t)(whalf * 4) * 8192;
    bk00 = *(const short8*)(Kt0 + (size_t)(0 * 16 + c) * 64 + 0 * 32 + q * 8);
    bk01 = *(const short8*)(Kt0 + (size_t)(0 * 16 + c) * 64 + 1 * 32 + q * 8);
    bk10 = *(const short8*)(Kt0 + (size_t)(1 * 16 + c) * 64 + 0 * 32 + q * 8);
    bk11 = *(const short8*)(Kt0 + (size_t)(1 * 16 + c) * 64 + 1 * 32 + q * 8);
  }

#pragma unroll
  for (int ph = 0; ph < 16; ph++) {
    const int kt = whalf * 4 + (ph >> 2);
    const int j = ph & 3;
    const unsigned char* cp = cbt + (size_t)kt * 4096;

    // ---- top: V loads for THIS phase (consumed by PV at the bottom) ----
    short8 vv0 = *(const short8*)(Vb + (size_t)(0 * 16 + c) * 1024 + kt * 128 + j * 32 + q * 8);
    short8 vv1 = *(const short8*)(Vb + (size_t)(1 * 16 + c) * 1024 + kt * 128 + j * 32 + q * 8);
    short8 vv2 = *(const short8*)(Vb + (size_t)(2 * 16 + c) * 1024 + kt * 128 + j * 32 + q * 8);
    short8 vv3 = *(const short8*)(Vb + (size_t)(3 * 16 + c) * 1024 + kt * 128 + j * 32 + q * 8);
    uint2 cw0 = *(const uint2*)(cp + j * 8);        // st=0 codes
    uint2 cw1 = *(const uint2*)(cp + 32 + j * 8);   // st=1 codes

    // ---- swapped QK^T on prefetched K: lane holds S[q=c][k] ----
    floatx4 s2[2][2];
    s2[0][0] = (floatx4)(0.0f); s2[0][1] = (floatx4)(0.0f);
    s2[1][0] = (floatx4)(0.0f); s2[1][1] = (floatx4)(0.0f);
    s2[0][0] = MFMA16(bk00, aq[0][0], s2[0][0]);
    s2[1][0] = MFMA16(bk00, aq[1][0], s2[1][0]);
    s2[0][0] = MFMA16(bk01, aq[0][1], s2[0][0]);
    s2[1][0] = MFMA16(bk01, aq[1][1], s2[1][0]);
    s2[0][1] = MFMA16(bk10, aq[0][0], s2[0][1]);
    s2[1][1] = MFMA16(bk10, aq[1][0], s2[1][1]);
    s2[0][1] = MFMA16(bk11, aq[0][1], s2[0][1]);
    s2[1][1] = MFMA16(bk11, aq[1][1], s2[1][1]);

    // ---- prefetch K for the NEXT phase (WAR on bk regs is issue-safe) ----
    if (ph < 15) {
      const int phn = ph + 1;
      const int ktn = whalf * 4 + (phn >> 2);
      const int jn = phn & 3;
      const unsigned short* Ktn = Kb + (size_t)ktn * 8192;
      bk00 = *(const short8*)(Ktn + (size_t)((2 * jn + 0) * 16 + c) * 64 + 0 * 32 + q * 8);
      bk01 = *(const short8*)(Ktn + (size_t)((2 * jn + 0) * 16 + c) * 64 + 1 * 32 + q * 8);
      bk10 = *(const short8*)(Ktn + (size_t)((2 * jn + 1) * 16 + c) * 64 + 0 * 32 + q * 8);
      bk11 = *(const short8*)(Ktn + (size_t)((2 * jn + 1) * 16 + c) * 64 + 1 * 32 + q * 8);
    }

    // ---- exp -> cvt_pk -> b64 P write + scalar row sums ----
#pragma unroll
    for (int st = 0; st < 2; st++) {
#pragma unroll
      for (int u = 0; u < 2; u++) {
        unsigned w = st ? (u ? cw1.y : cw1.x) : (u ? cw0.y : cw0.x);
        float ev[4];
#pragma unroll
        for (int r = 0; r < 4; r++) {
          int code = (w >> (r * 8)) & 0xff;
          float ee = (h >= code) ? exp2f(s2[st][u][r] * 0.1803368801111362f) : 0.0f;
          rsum[st] += ee;
          ev[r] = ee;
        }
        unsigned p0, p1;
        asm("v_cvt_pk_bf16_f32 %0, %1, %2" : "=v"(p0) : "v"(ev[0]), "v"(ev[1]));
        asm("v_cvt_pk_bf16_f32 %0, %1, %2" : "=v"(p1) : "v"(ev[2]), "v"(ev[3]));
        uint2 pk; pk.x = p0; pk.y = p1;
        *(uint2*)(&Pw[(st * 16 + c) * 132 + (2 * j + u) * 16 + q * 4]) = pk;
      }
    }

    __builtin_amdgcn_sched_barrier(0);   // phase waist: write side || read side

    // ---- PV: read back own P (lgkm) x resident V frags ----
    short8 ap0 = *(const short8*)(&Pw[(size_t)c * 132 + j * 32 + q * 8]);
    short8 ap1 = *(const short8*)(&Pw[(size_t)(16 + c) * 132 + j * 32 + q * 8]);
    o[0][0] = MFMA16(ap0, vv0, o[0][0]);
    o[1][0] = MFMA16(ap1, vv0, o[1][0]);
    o[0][1] = MFMA16(ap0, vv1, o[0][1]);
    o[1][1] = MFMA16(ap1, vv1, o[1][1]);
    o[0][2] = MFMA16(ap0, vv2, o[0][2]);
    o[1][2] = MFMA16(ap1, vv2, o[1][2]);
    o[0][3] = MFMA16(ap0, vv3, o[0][3]);
    o[1][3] = MFMA16(ap1, vv3, o[1][3]);
  }

  // ---- merge kt-half partials: waves 2,3 -> LDS, waves 0,1 accumulate ----
  // chunks 0..7 = o[st][ci] (float4), chunk 8 = rsum[0..1] (float2). 18 KB.
  float* Pf = (float*)&P[0][0];
  __syncthreads();
  if (whalf == 1) {
#pragma unroll
    for (int st = 0; st < 2; st++)
#pragma unroll
      for (int ci = 0; ci < 4; ci++)
        *(floatx4*)&Pf[(((wsub * 9 + st * 4 + ci) * 64) + lane) * 4] = o[st][ci];
    float2 rr; rr.x = rsum[0]; rr.y = rsum[1];
    *(float2*)&Pf[(((wsub * 9 + 8) * 64) + lane) * 4] = rr;
  }
  __syncthreads();
  if (whalf == 1) return;

#pragma unroll
  for (int st = 0; st < 2; st++)
#pragma unroll
    for (int ci = 0; ci < 4; ci++) {
      floatx4 p = *(const floatx4*)&Pf[(((wsub * 9 + st * 4 + ci) * 64) + lane) * 4];
      o[st][ci] += p;
    }
  {
    float2 pr = *(const float2*)&Pf[(((wsub * 9 + 8) * 64) + lane) * 4];
    rsum[0] += pr.x; rsum[1] += pr.y;
  }

  // ---- normalize + write ----
  // Full row sum for q-row st*16+c: reduce partials across the 4 hi-groups.
  float inv2[2];
#pragma unroll
  for (int st = 0; st < 2; st++) {
    float v = rsum[st];
    v += __shfl_xor(v, 16);
    v += __shfl_xor(v, 32);
    inv2[st] = 1.0f / v;
  }
  // redistribute: lane (c,q) stores rows q*4+r -> needs inv from lane c'=q*4+r
  const int sb = (lane & 48) + ((lane & 48) >> 2);
  float iv[2][4];
#pragma unroll
  for (int st = 0; st < 2; st++)
#pragma unroll
    for (int r = 0; r < 4; r++) iv[st][r] = __shfl(inv2[st], sb + r);

#pragma unroll
  for (int st = 0; st < 2; st++)
#pragma unroll
    for (int r = 0; r < 4; r++) {
      int n = rbase + st * 16 + q * 4 + r;
      size_t ob = ((size_t)((b << 10) + n)) * 512 + h * 64;
#pragma unroll
      for (int ci = 0; ci < 4; ci++)
        AO[ob + ci * 16 + c] = f2bf(o[st][ci][r] * iv[st][r]);
    }
}

// ---------------- launcher ----------------
extern "C" void kernel_launch(void* const* d_in, const int* in_sizes, int n_in,
                              void* d_out, int out_size, void* d_ws, size_t ws_size,
                              hipStream_t stream) {
  const float* query = (const float*)d_in[0];
  const float* key_  = (const float*)d_in[1];
  const float* value = (const float*)d_in[2];
  const float* dist  = (const float*)d_in[3];
  const int*   mask  = (const int*)d_in[4];
  const float* Wq = (const float*)d_in[5];
  const float* bq = (const float*)d_in[6];
  const float* Wk = (const float*)d_in[7];
  const float* bk = (const float*)d_in[8];
  const float* Wv = (const float*)d_in[9];
  const float* bv = (const float*)d_in[10];
  const float* Wo = (const float*)d_in[11];
  const float* bo = (const float*)d_in[12];

  char* ws = (char*)d_ws;
  size_t off = 0;
  auto alloc = [&](size_t bytes) -> char* {
    char* p = ws + off;
    off += (bytes + 255) & ~(size_t)255;
    return p;
  };
  const size_t NQKV = 8192ull * 512;
  unsigned short* wq16 = (unsigned short*)alloc(512ull * 512 * 2);
  unsigned short* wk16 = (unsigned short*)alloc(512ull * 512 * 2);
  unsigned short* wv16 = (unsigned short*)alloc(512ull * 512 * 2);
  unsigned short* wo16 = (unsigned short*)alloc(512ull * 512 * 2);
  unsigned short* Qh = (unsigned short*)alloc(NQKV * 2);
  unsigned short* Kh = (unsigned short*)alloc(NQKV * 2);
  unsigned short* Vt = (unsigned short*)alloc(NQKV * 2);
  unsigned short* AO = (unsigned short*)alloc(NQKV * 2);
  unsigned char*  codesP = (unsigned char*)alloc(8ull * 1024 * 1024);
  unsigned short* Qi = (unsigned short*)alloc(NQKV * 2);   // bf16-cast inputs
  unsigned short* Ki = (unsigned short*)alloc(NQKV * 2);
  unsigned short* Vi = (unsigned short*)alloc(NQKV * 2);

  prep_kernel<<<9216, 256, 0, stream>>>(dist, mask, codesP, Wq, Wk, Wv, Wo,
                                        wq16, wk16, wv16, wo16,
                                        query, key_, value, Qi, Ki, Vi);
  qkv_gemm<<<dim3(128, 4, 3), 256, 0, stream>>>(Qi, Ki, Vi, wq16, wk16, wv16,
                                                bq, bk, bv, Qh, Kh, Vt);
  attn_kernel<<<1024, 256, 0, stream>>>(Qh, Kh, Vt, codesP, AO);
  out_gemm<<<dim3(128, 4), 256, 0, stream>>>(AO, wo16, bo, (float*)d_out);
}